// Round 1
// 700.025 us; speedup vs baseline: 1.0239x; 1.0239x over previous
//
#include <hip/hip_runtime.h>
#include <hip/hip_bf16.h>
#include <math.h>

#define N_ENT 100000
#define NB    50000
#define NE    200000
#define RR    8
#define NETOT (RR * NE)          // 1,600,000
#define NSEG  (RR * N_ENT)       // 800,000

typedef float f32x4  __attribute__((ext_vector_type(4)));
typedef short s16x8  __attribute__((ext_vector_type(8)));

__device__ __forceinline__ void split2(float x, short& h, short& l)
{
    unsigned uh = __float_as_uint(x) & 0xffff0000u;
    h = (short)(uh >> 16);
    float r = x - __uint_as_float(uh);
    l = (short)(__float_as_uint(r) >> 16);
}

// ---------------- K pre-transform: Kt[r][o][d] = K[r][d][o], split hi/lo bf16 ---
__global__ __launch_bounds__(256)
void ktconv_k(const float* __restrict__ rel_k, const float* __restrict__ self_k,
              short* __restrict__ Kth, short* __restrict__ Ktl)
{
    const int r = blockIdx.x;              // 0..8, 8 == self
    const float* src = (r < 8) ? rel_k + (size_t)r * 16384 : self_k;
    short* oh = Kth + (size_t)r * 16384;
    short* ol = Ktl + (size_t)r * 16384;
    for (int i = 0; i < 64; ++i) {
        int ix = i * 256 + threadIdx.x;    // 0..16383
        int d = ix >> 7, o = ix & 127;
        short h, l;
        split2(src[ix], h, l);
        oh[o * 128 + d] = h;
        ol[o * 128 + d] = l;
    }
}

// ---------------- MFMA GEMM: out[rows x 128] = X @ Kstack (+ optional epilogues)
// block: 256 thr / 4 waves, 128 rows per block.
// X row stride = xstride floats; K = nkc chunks of 128 (each chunk = one 128x128
// transposed hi/lo Kt staged into LDS).
// FINAL: out = sigmoid(acc + Abuf[idx[row]])   ACCUM: out += acc   else: out = acc
template<bool FINAL, bool ACCUM>
__global__ __launch_bounds__(256)
void gemm_mfma_k(const float* __restrict__ X, int xstride,
                 const short* __restrict__ Kth, const short* __restrict__ Ktl,
                 int nkc,
                 const float* __restrict__ Abuf, const int* __restrict__ idx,
                 float* __restrict__ out, int nrows)
{
    __shared__ short Bh[128][136];   // padded: 272B row stride -> conflict-free-ish
    __shared__ short Bl[128][136];

    const int t     = threadIdx.x;
    const int wv    = t >> 6;
    const int lane  = t & 63;
    const int col16 = lane & 15;
    const int g     = lane >> 4;          // k-group 0..3
    const int rowbase = blockIdx.x * 128 + wv * 32;

    f32x4 acc[2][8];
#pragma unroll
    for (int m = 0; m < 2; ++m)
#pragma unroll
        for (int c = 0; c < 8; ++c) acc[m][c] = (f32x4){0.f, 0.f, 0.f, 0.f};

    for (int kc = 0; kc < nkc; ++kc) {
        __syncthreads();                  // protect LDS from previous chunk's reads
        {
            const s16x8* gh = (const s16x8*)(Kth + (size_t)kc * 16384);
            const s16x8* gl = (const s16x8*)(Ktl + (size_t)kc * 16384);
#pragma unroll
            for (int i = 0; i < 8; ++i) {
                int f = t + i * 256;          // 0..2047
                int o = f >> 4, c = f & 15;
                *(s16x8*)&Bh[o][c * 8] = gh[f];
                *(s16x8*)&Bl[o][c * 8] = gl[f];
            }
        }
        __syncthreads();

#pragma unroll
        for (int s = 0; s < 4; ++s) {
            s16x8 ah[2], al[2];
#pragma unroll
            for (int m = 0; m < 2; ++m) {
                int r = rowbase + m * 16 + col16;
                if (r > nrows - 1) r = nrows - 1;
                const float* xp = X + (size_t)r * xstride + kc * 128 + s * 32 + g * 8;
                float4 u0 = *(const float4*)xp;
                float4 u1 = *(const float4*)(xp + 4);
                float u[8] = {u0.x, u0.y, u0.z, u0.w, u1.x, u1.y, u1.z, u1.w};
#pragma unroll
                for (int j = 0; j < 8; ++j) {
                    short h, l; split2(u[j], h, l);
                    ah[m][j] = h; al[m][j] = l;
                }
            }
#pragma unroll
            for (int c = 0; c < 8; ++c) {
                s16x8 bh = *(const s16x8*)&Bh[c * 16 + col16][s * 32 + g * 8];
                s16x8 bl = *(const s16x8*)&Bl[c * 16 + col16][s * 32 + g * 8];
#pragma unroll
                for (int m = 0; m < 2; ++m) {
                    acc[m][c] = __builtin_amdgcn_mfma_f32_16x16x32_bf16(ah[m], bh, acc[m][c], 0, 0, 0);
                    acc[m][c] = __builtin_amdgcn_mfma_f32_16x16x32_bf16(ah[m], bl, acc[m][c], 0, 0, 0);
                    acc[m][c] = __builtin_amdgcn_mfma_f32_16x16x32_bf16(al[m], bh, acc[m][c], 0, 0, 0);
                }
            }
        }
    }

    // epilogue: C layout col=lane&15, row=g*4+reg
#pragma unroll
    for (int m = 0; m < 2; ++m) {
#pragma unroll
        for (int j = 0; j < 4; ++j) {
            int row = rowbase + m * 16 + g * 4 + j;
            if (row >= nrows) continue;
            float* op = out + (size_t)row * 128;
            if (FINAL) {
                int gi = idx[row];
                const float* Ar = Abuf + (size_t)gi * 128;
#pragma unroll
                for (int c = 0; c < 8; ++c) {
                    int col = c * 16 + col16;
                    float x = acc[m][c][j] + Ar[col];
                    op[col] = 1.f / (1.f + __expf(-x));
                }
            } else if (ACCUM) {
#pragma unroll
                for (int c = 0; c < 8; ++c) {
                    int col = c * 16 + col16;
                    op[col] += acc[m][c][j];
                }
            } else {
#pragma unroll
                for (int c = 0; c < 8; ++c)
                    op[c * 16 + col16] = acc[m][c][j];
            }
        }
    }
}

// ---------------- CSR build ----------------
__global__ __launch_bounds__(256)
void count_k(const int* __restrict__ edge_src, unsigned* __restrict__ cnt)
{
    int g = blockIdx.x * 256 + threadIdx.x;
    int r = g / NE;
    int src = edge_src[g];
    atomicAdd(&cnt[r * N_ENT + src], 1u);
}

__global__ __launch_bounds__(256)
void scan1_k(const unsigned* __restrict__ cnt, unsigned* __restrict__ offs,
             unsigned* __restrict__ bsum)
{
    __shared__ unsigned s[256];
    const int t = threadIdx.x;
    const int base = blockIdx.x * 1024;
    unsigned v[4], sum = 0;
#pragma unroll
    for (int i = 0; i < 4; ++i) {
        int ix = base + t * 4 + i;
        v[i] = (ix < NSEG) ? cnt[ix] : 0u;
        sum += v[i];
    }
    s[t] = sum; __syncthreads();
    for (int off = 1; off < 256; off <<= 1) {
        unsigned x = (t >= off) ? s[t - off] : 0u;
        __syncthreads();
        s[t] += x;
        __syncthreads();
    }
    unsigned run = s[t] - sum;
#pragma unroll
    for (int i = 0; i < 4; ++i) {
        int ix = base + t * 4 + i;
        if (ix < NSEG) offs[ix] = run;
        run += v[i];
    }
    if (t == 255) bsum[blockIdx.x] = s[255];
}

__global__ __launch_bounds__(256)
void scan2_k(unsigned* __restrict__ bsum, int nb)
{
    __shared__ unsigned s[256];
    __shared__ unsigned carry;
    const int t = threadIdx.x;
    if (t == 0) carry = 0;
    __syncthreads();
    for (int base = 0; base < nb; base += 256) {
        unsigned v = (base + t < nb) ? bsum[base + t] : 0u;
        s[t] = v; __syncthreads();
        for (int off = 1; off < 256; off <<= 1) {
            unsigned x = (t >= off) ? s[t - off] : 0u;
            __syncthreads();
            s[t] += x;
            __syncthreads();
        }
        unsigned tot = s[255];
        unsigned excl = s[t] - v + carry;
        if (base + t < nb) bsum[base + t] = excl;
        __syncthreads();
        if (t == 0) carry += tot;
        __syncthreads();
    }
}

__global__ __launch_bounds__(256)
void scan3_k(unsigned* __restrict__ offs, const unsigned* __restrict__ bsum)
{
    const int base = blockIdx.x * 1024;
    unsigned add = bsum[blockIdx.x];
#pragma unroll
    for (int i = 0; i < 4; ++i) {
        int ix = base + threadIdx.x * 4 + i;
        if (ix < NSEG) offs[ix] += add;
    }
    if (blockIdx.x == 0 && threadIdx.x == 0) offs[NSEG] = NETOT;
}

__global__ __launch_bounds__(256)
void fill_k(const int* __restrict__ edge_src, const int* __restrict__ edge_dst,
            const float* __restrict__ edge_val,
            const unsigned* __restrict__ offs, unsigned* __restrict__ cursor,
            int2* __restrict__ recs)
{
    int g = blockIdx.x * 256 + threadIdx.x;
    int r = g / NE;
    int src = edge_src[g];
    int seg = r * N_ENT + src;
    unsigned pos = offs[seg] + atomicAdd(&cursor[seg], 1u);
    int2 rec;
    rec.x = edge_dst[g];
    rec.y = __float_as_int(edge_val[g]);
    recs[pos] = rec;
}

// ---------------- fused aggregate-first segment-sum ----------------
// one wave per (relation j, entity s); B[s][j*128 + :] = sum val * emb[dst]
__global__ __launch_bounds__(256)
void segsum_k(const unsigned* __restrict__ offs_r, const int2* __restrict__ recs,
              const float* __restrict__ emb, float* __restrict__ B, int nrel)
{
    int wid  = (blockIdx.x * 256 + threadIdx.x) >> 6;   // 0 .. nrel*N_ENT-1
    int lane = threadIdx.x & 63;
    int j = wid / N_ENT;          // relation within group
    int s = wid - j * N_ENT;      // entity
    unsigned e0 = offs_r[wid];
    unsigned e1 = offs_r[wid + 1];
    float2 acc = {0.f, 0.f};
    for (unsigned e = e0; e < e1; ++e) {
        int2 rec = recs[e];
        float v = __int_as_float(rec.y);
        float2 y = *(const float2*)(emb + (size_t)rec.x * 128 + lane * 2);
        acc.x = fmaf(v, y.x, acc.x);
        acc.y = fmaf(v, y.y, acc.y);
    }
    *(float2*)(B + ((size_t)s * nrel + j) * 128 + lane * 2) = acc;
}

extern "C" void kernel_launch(void* const* d_in, const int* in_sizes, int n_in,
                              void* d_out, int out_size, void* d_ws, size_t ws_size,
                              hipStream_t stream)
{
    const float* emb      = (const float*)d_in[0];
    const float* head_e   = (const float*)d_in[1];
    const float* tail_e   = (const float*)d_in[2];
    const float* rel_k    = (const float*)d_in[3];
    const float* self_k   = (const float*)d_in[4];
    const float* edge_val = (const float*)d_in[5];
    const int*   head_idx = (const int*)d_in[6];
    const int*   tail_idx = (const int*)d_in[7];
    const int*   edge_src = (const int*)d_in[8];
    const int*   edge_dst = (const int*)d_in[9];
    float* out = (float*)d_out;

    // workspace layout (each region 256B-aligned)
    char* p = (char*)d_ws;
    auto take = [&](size_t bytes) -> char* {
        char* q = p; p += (bytes + 255) & ~(size_t)255; return q;
    };
    float*    A    = (float*)take((size_t)N_ENT * 128 * sizeof(float));     // 51.2 MB
    int2*     recs = (int2*)take((size_t)NETOT * sizeof(int2));             // 12.8 MB
    unsigned* cnt  = (unsigned*)take((size_t)NSEG * sizeof(unsigned));      //  3.2 MB
    unsigned* offs = (unsigned*)take(((size_t)NSEG + 1) * sizeof(unsigned));//  3.2 MB
    unsigned* bsum = (unsigned*)take(1024 * sizeof(unsigned));
    short*    Kth  = (short*)take((size_t)9 * 16384 * sizeof(short));       //  0.3 MB
    short*    Ktl  = (short*)take((size_t)9 * 16384 * sizeof(short));       //  0.3 MB
    float*    Bbuf = (float*)p;                                             // rest

    // adaptive relation-group size: how many 51.2 MB B_r slices fit?
    size_t used    = (size_t)(p - (char*)d_ws);
    size_t avail   = (ws_size > used) ? ws_size - used : 0;
    size_t per_rel = (size_t)N_ENT * 128 * sizeof(float);
    int RPG = (int)(avail / per_rel);
    if (RPG > RR) RPG = RR;
    if (RPG < 1)  RPG = 1;   // old kernel needed more ws than this path's minimum

    const int NB1 = (NSEG + 1023) / 1024;   // 782
    dim3 blk(256);

    // ---- K transform + CSR build ----
    ktconv_k<<<9, blk, 0, stream>>>(rel_k, self_k, Kth, Ktl);
    hipMemsetAsync(cnt, 0, (size_t)NSEG * sizeof(unsigned), stream);
    count_k<<<NETOT / 256, blk, 0, stream>>>(edge_src, cnt);
    scan1_k<<<NB1, blk, 0, stream>>>(cnt, offs, bsum);
    scan2_k<<<1, blk, 0, stream>>>(bsum, NB1);
    scan3_k<<<NB1, blk, 0, stream>>>(offs, bsum);
    hipMemsetAsync(cnt, 0, (size_t)NSEG * sizeof(unsigned), stream);
    fill_k<<<NETOT / 256, blk, 0, stream>>>(edge_src, edge_dst, edge_val,
                                            offs, cnt, recs);

    // ---- aggregate-first: B_r = segsum_r(emb); A (+)= B @ vstack(K_r) ----
    const int gy = (N_ENT + 127) / 128;     // 782
    int first = 1;
    for (int g0 = 0; g0 < RR; ) {
        int nr = (RR - g0 < RPG) ? RR - g0 : RPG;
        int gs = nr * (N_ENT / 4);          // one wave per (rel, entity)
        segsum_k<<<gs, blk, 0, stream>>>(offs + (size_t)g0 * N_ENT, recs,
                                         emb, Bbuf, nr);
        if (first)
            gemm_mfma_k<false, false><<<gy, blk, 0, stream>>>(
                Bbuf, nr * 128,
                Kth + (size_t)g0 * 16384, Ktl + (size_t)g0 * 16384, nr,
                nullptr, nullptr, A, N_ENT);
        else
            gemm_mfma_k<false, true><<<gy, blk, 0, stream>>>(
                Bbuf, nr * 128,
                Kth + (size_t)g0 * 16384, Ktl + (size_t)g0 * 16384, nr,
                nullptr, nullptr, A, N_ENT);
        first = 0;
        g0 += nr;
    }

    // ---- final: out = sigmoid(X @ S + A[idx]) ----
    const int gb = (NB + 127) / 128;        // 391
    gemm_mfma_k<true, false><<<gb, blk, 0, stream>>>(
        head_e, 128, Kth + (size_t)8 * 16384, Ktl + (size_t)8 * 16384, 1,
        A, head_idx, out, NB);
    gemm_mfma_k<true, false><<<gb, blk, 0, stream>>>(
        tail_e, 128, Kth + (size_t)8 * 16384, Ktl + (size_t)8 * 16384, 1,
        A, tail_idx, out + (size_t)NB * 128, NB);
}

// Round 2
// 688.862 us; speedup vs baseline: 1.0405x; 1.0162x over previous
//
#include <hip/hip_runtime.h>
#include <hip/hip_bf16.h>
#include <math.h>

#define N_ENT 100000
#define NB    50000
#define NE    200000
#define RR    8
#define NETOT (RR * NE)          // 1,600,000
#define NSEG  (RR * N_ENT)       // 800,000

typedef float f32x4  __attribute__((ext_vector_type(4)));
typedef short s16x8  __attribute__((ext_vector_type(8)));

__device__ __forceinline__ void split2(float x, short& h, short& l)
{
    unsigned uh = __float_as_uint(x) & 0xffff0000u;
    h = (short)(uh >> 16);
    float r = x - __uint_as_float(uh);
    l = (short)(__float_as_uint(r) >> 16);
}

// ---------------- K pre-transform: Kt[r][o][d] = K[r][d][o], split hi/lo bf16 ---
__global__ __launch_bounds__(256)
void ktconv_k(const float* __restrict__ rel_k, const float* __restrict__ self_k,
              short* __restrict__ Kth, short* __restrict__ Ktl)
{
    const int r = blockIdx.x;              // 0..8, 8 == self
    const float* src = (r < 8) ? rel_k + (size_t)r * 16384 : self_k;
    short* oh = Kth + (size_t)r * 16384;
    short* ol = Ktl + (size_t)r * 16384;
    for (int i = 0; i < 64; ++i) {
        int ix = i * 256 + threadIdx.x;    // 0..16383
        int d = ix >> 7, o = ix & 127;
        short h, l;
        split2(src[ix], h, l);
        oh[o * 128 + d] = h;
        ol[o * 128 + d] = l;
    }
}

// ---------------- MFMA GEMM: out[rows x 128] = X @ Kstack (+ optional epilogues)
// block: 256 thr / 4 waves, 128 rows per block.
// X row stride = xstride floats; K = nkc chunks of 128 (each chunk = one 128x128
// transposed hi/lo Kt staged into LDS).
// FINAL: out = sigmoid(acc + Abuf[idx[row]])   ACCUM: out += acc   else: out = acc
template<bool FINAL, bool ACCUM>
__global__ __launch_bounds__(256)
void gemm_mfma_k(const float* __restrict__ X, int xstride,
                 const short* __restrict__ Kth, const short* __restrict__ Ktl,
                 int nkc,
                 const float* __restrict__ Abuf, const int* __restrict__ idx,
                 float* __restrict__ out, int nrows)
{
    __shared__ short Bh[128][136];   // padded: 272B row stride -> conflict-free-ish
    __shared__ short Bl[128][136];

    const int t     = threadIdx.x;
    const int wv    = t >> 6;
    const int lane  = t & 63;
    const int col16 = lane & 15;
    const int g     = lane >> 4;          // k-group 0..3
    const int rowbase = blockIdx.x * 128 + wv * 32;

    f32x4 acc[2][8];
#pragma unroll
    for (int m = 0; m < 2; ++m)
#pragma unroll
        for (int c = 0; c < 8; ++c) acc[m][c] = (f32x4){0.f, 0.f, 0.f, 0.f};

    for (int kc = 0; kc < nkc; ++kc) {
        __syncthreads();                  // protect LDS from previous chunk's reads
        {
            const s16x8* gh = (const s16x8*)(Kth + (size_t)kc * 16384);
            const s16x8* gl = (const s16x8*)(Ktl + (size_t)kc * 16384);
#pragma unroll
            for (int i = 0; i < 8; ++i) {
                int f = t + i * 256;          // 0..2047
                int o = f >> 4, c = f & 15;
                *(s16x8*)&Bh[o][c * 8] = gh[f];
                *(s16x8*)&Bl[o][c * 8] = gl[f];
            }
        }
        __syncthreads();

#pragma unroll
        for (int s = 0; s < 4; ++s) {
            s16x8 ah[2], al[2];
#pragma unroll
            for (int m = 0; m < 2; ++m) {
                int r = rowbase + m * 16 + col16;
                if (r > nrows - 1) r = nrows - 1;
                const float* xp = X + (size_t)r * xstride + kc * 128 + s * 32 + g * 8;
                float4 u0 = *(const float4*)xp;
                float4 u1 = *(const float4*)(xp + 4);
                float u[8] = {u0.x, u0.y, u0.z, u0.w, u1.x, u1.y, u1.z, u1.w};
#pragma unroll
                for (int j = 0; j < 8; ++j) {
                    short h, l; split2(u[j], h, l);
                    ah[m][j] = h; al[m][j] = l;
                }
            }
#pragma unroll
            for (int c = 0; c < 8; ++c) {
                s16x8 bh = *(const s16x8*)&Bh[c * 16 + col16][s * 32 + g * 8];
                s16x8 bl = *(const s16x8*)&Bl[c * 16 + col16][s * 32 + g * 8];
#pragma unroll
                for (int m = 0; m < 2; ++m) {
                    acc[m][c] = __builtin_amdgcn_mfma_f32_16x16x32_bf16(ah[m], bh, acc[m][c], 0, 0, 0);
                    acc[m][c] = __builtin_amdgcn_mfma_f32_16x16x32_bf16(ah[m], bl, acc[m][c], 0, 0, 0);
                    acc[m][c] = __builtin_amdgcn_mfma_f32_16x16x32_bf16(al[m], bh, acc[m][c], 0, 0, 0);
                }
            }
        }
    }

    // epilogue: C layout col=lane&15, row=g*4+reg
#pragma unroll
    for (int m = 0; m < 2; ++m) {
#pragma unroll
        for (int j = 0; j < 4; ++j) {
            int row = rowbase + m * 16 + g * 4 + j;
            if (row >= nrows) continue;
            float* op = out + (size_t)row * 128;
            if (FINAL) {
                int gi = idx[row];
                const float* Ar = Abuf + (size_t)gi * 128;
#pragma unroll
                for (int c = 0; c < 8; ++c) {
                    int col = c * 16 + col16;
                    float x = acc[m][c][j] + Ar[col];
                    op[col] = 1.f / (1.f + __expf(-x));
                }
            } else if (ACCUM) {
#pragma unroll
                for (int c = 0; c < 8; ++c) {
                    int col = c * 16 + col16;
                    op[col] += acc[m][c][j];
                }
            } else {
#pragma unroll
                for (int c = 0; c < 8; ++c)
                    op[c * 16 + col16] = acc[m][c][j];
            }
        }
    }
}

// ---------------- CSR build ----------------
__global__ __launch_bounds__(256)
void count_k(const int* __restrict__ edge_src, unsigned* __restrict__ cnt)
{
    int g = blockIdx.x * 256 + threadIdx.x;
    int r = g / NE;
    int src = edge_src[g];
    atomicAdd(&cnt[r * N_ENT + src], 1u);
}

__global__ __launch_bounds__(256)
void scan1_k(const unsigned* __restrict__ cnt, unsigned* __restrict__ offs,
             unsigned* __restrict__ bsum)
{
    __shared__ unsigned s[256];
    const int t = threadIdx.x;
    const int base = blockIdx.x * 1024;
    unsigned v[4], sum = 0;
#pragma unroll
    for (int i = 0; i < 4; ++i) {
        int ix = base + t * 4 + i;
        v[i] = (ix < NSEG) ? cnt[ix] : 0u;
        sum += v[i];
    }
    s[t] = sum; __syncthreads();
    for (int off = 1; off < 256; off <<= 1) {
        unsigned x = (t >= off) ? s[t - off] : 0u;
        __syncthreads();
        s[t] += x;
        __syncthreads();
    }
    unsigned run = s[t] - sum;
#pragma unroll
    for (int i = 0; i < 4; ++i) {
        int ix = base + t * 4 + i;
        if (ix < NSEG) offs[ix] = run;
        run += v[i];
    }
    if (t == 255) bsum[blockIdx.x] = s[255];
}

__global__ __launch_bounds__(256)
void scan2_k(unsigned* __restrict__ bsum, int nb)
{
    __shared__ unsigned s[256];
    __shared__ unsigned carry;
    const int t = threadIdx.x;
    if (t == 0) carry = 0;
    __syncthreads();
    for (int base = 0; base < nb; base += 256) {
        unsigned v = (base + t < nb) ? bsum[base + t] : 0u;
        s[t] = v; __syncthreads();
        for (int off = 1; off < 256; off <<= 1) {
            unsigned x = (t >= off) ? s[t - off] : 0u;
            __syncthreads();
            s[t] += x;
            __syncthreads();
        }
        unsigned tot = s[255];
        unsigned excl = s[t] - v + carry;
        if (base + t < nb) bsum[base + t] = excl;
        __syncthreads();
        if (t == 0) carry += tot;
        __syncthreads();
    }
}

__global__ __launch_bounds__(256)
void scan3_k(unsigned* __restrict__ offs, const unsigned* __restrict__ bsum)
{
    const int base = blockIdx.x * 1024;
    unsigned add = bsum[blockIdx.x];
#pragma unroll
    for (int i = 0; i < 4; ++i) {
        int ix = base + threadIdx.x * 4 + i;
        if (ix < NSEG) offs[ix] += add;
    }
    if (blockIdx.x == 0 && threadIdx.x == 0) offs[NSEG] = NETOT;
}

__global__ __launch_bounds__(256)
void fill_k(const int* __restrict__ edge_src, const int* __restrict__ edge_dst,
            const float* __restrict__ edge_val,
            const unsigned* __restrict__ offs, unsigned* __restrict__ cursor,
            int2* __restrict__ recs)
{
    int g = blockIdx.x * 256 + threadIdx.x;
    int r = g / NE;
    int src = edge_src[g];
    int seg = r * N_ENT + src;
    unsigned pos = offs[seg] + atomicAdd(&cursor[seg], 1u);
    int2 rec;
    rec.x = edge_dst[g];
    rec.y = __float_as_int(edge_val[g]);
    recs[pos] = rec;
}

// ---------------- fused aggregate-first segment-sum ----------------
// one wave per segment s, covering all NR relations of the group.
// Batched prefetch (T recs/relation, then T gathers/relation) collapses the
// dependent-load chain; all guards are wave-uniform. FMA order per segment
// is identical to the serial walk -> bitwise-same numerics.
template<int NR>
__global__ __launch_bounds__(256)
void segsum_k(const unsigned* __restrict__ offs_r, const int2* __restrict__ recs,
              const float* __restrict__ emb, float* __restrict__ B)
{
    constexpr int T = 4;
    const int s    = (blockIdx.x * 256 + threadIdx.x) >> 6;   // segment id
    const int lane = threadIdx.x & 63;
    if (s >= N_ENT) return;

    unsigned e0[NR]; int n[NR];
#pragma unroll
    for (int j = 0; j < NR; ++j) {
        unsigned a = offs_r[(size_t)j * N_ENT + s];
        unsigned b = offs_r[(size_t)j * N_ENT + s + 1];
        e0[j] = a; n[j] = (int)(b - a);
    }

    // phase 1: batch-load up to T records per relation (independent loads)
    int2 rec[NR][T];
#pragma unroll
    for (int j = 0; j < NR; ++j)
#pragma unroll
        for (int i = 0; i < T; ++i)
            if (i < n[j]) rec[j][i] = recs[e0[j] + i];

    // phase 2: batch-issue all emb-row gathers (independent 512B loads)
    float2 y[NR][T];
#pragma unroll
    for (int j = 0; j < NR; ++j)
#pragma unroll
        for (int i = 0; i < T; ++i)
            if (i < n[j])
                y[j][i] = *(const float2*)(emb + (size_t)rec[j][i].x * 128 + lane * 2);

    // phase 3: accumulate (same per-segment order as a serial walk)
    float2 acc[NR];
#pragma unroll
    for (int j = 0; j < NR; ++j) acc[j] = (float2){0.f, 0.f};
#pragma unroll
    for (int j = 0; j < NR; ++j)
#pragma unroll
        for (int i = 0; i < T; ++i)
            if (i < n[j]) {
                float v = __int_as_float(rec[j][i].y);
                acc[j].x = fmaf(v, y[j][i].x, acc[j].x);
                acc[j].y = fmaf(v, y[j][i].y, acc[j].y);
            }

    // tail: segments with > T edges (rare, wave-uniform)
#pragma unroll
    for (int j = 0; j < NR; ++j) {
        for (int i = T; i < n[j]; ++i) {
            int2 rc = recs[e0[j] + i];
            float v = __int_as_float(rc.y);
            float2 yy = *(const float2*)(emb + (size_t)rc.x * 128 + lane * 2);
            acc[j].x = fmaf(v, yy.x, acc[j].x);
            acc[j].y = fmaf(v, yy.y, acc[j].y);
        }
    }

#pragma unroll
    for (int j = 0; j < NR; ++j)
        *(float2*)(B + ((size_t)s * NR + j) * 128 + lane * 2) = acc[j];
}

static void launch_segsum(int nr, const unsigned* offs_r, const int2* recs,
                          const float* emb, float* B, hipStream_t stream)
{
    dim3 blk(256);
    const int blocks = (N_ENT * 64) / 256;   // 25000, exact
    switch (nr) {
    case 1: segsum_k<1><<<blocks, blk, 0, stream>>>(offs_r, recs, emb, B); break;
    case 2: segsum_k<2><<<blocks, blk, 0, stream>>>(offs_r, recs, emb, B); break;
    case 3: segsum_k<3><<<blocks, blk, 0, stream>>>(offs_r, recs, emb, B); break;
    default: segsum_k<4><<<blocks, blk, 0, stream>>>(offs_r, recs, emb, B); break;
    }
}

extern "C" void kernel_launch(void* const* d_in, const int* in_sizes, int n_in,
                              void* d_out, int out_size, void* d_ws, size_t ws_size,
                              hipStream_t stream)
{
    const float* emb      = (const float*)d_in[0];
    const float* head_e   = (const float*)d_in[1];
    const float* tail_e   = (const float*)d_in[2];
    const float* rel_k    = (const float*)d_in[3];
    const float* self_k   = (const float*)d_in[4];
    const float* edge_val = (const float*)d_in[5];
    const int*   head_idx = (const int*)d_in[6];
    const int*   tail_idx = (const int*)d_in[7];
    const int*   edge_src = (const int*)d_in[8];
    const int*   edge_dst = (const int*)d_in[9];
    float* out = (float*)d_out;

    // workspace layout (each region 256B-aligned)
    char* p = (char*)d_ws;
    auto take = [&](size_t bytes) -> char* {
        char* q = p; p += (bytes + 255) & ~(size_t)255; return q;
    };
    float*    A    = (float*)take((size_t)N_ENT * 128 * sizeof(float));     // 51.2 MB
    int2*     recs = (int2*)take((size_t)NETOT * sizeof(int2));             // 12.8 MB
    unsigned* cnt  = (unsigned*)take((size_t)NSEG * sizeof(unsigned));      //  3.2 MB
    unsigned* offs = (unsigned*)take(((size_t)NSEG + 1) * sizeof(unsigned));//  3.2 MB
    unsigned* bsum = (unsigned*)take(1024 * sizeof(unsigned));
    short*    Kth  = (short*)take((size_t)9 * 16384 * sizeof(short));       //  0.3 MB
    short*    Ktl  = (short*)take((size_t)9 * 16384 * sizeof(short));       //  0.3 MB
    float*    Bbuf = (float*)p;                                             // rest

    // adaptive relation-group size: how many 51.2 MB B_r slices fit?
    size_t used    = (size_t)(p - (char*)d_ws);
    size_t avail   = (ws_size > used) ? ws_size - used : 0;
    size_t per_rel = (size_t)N_ENT * 128 * sizeof(float);
    int RPG = (int)(avail / per_rel);
    if (RPG > 4) RPG = 4;    // template max; ILP gain saturates here
    if (RPG < 1) RPG = 1;

    const int NB1 = (NSEG + 1023) / 1024;   // 782
    dim3 blk(256);

    // ---- K transform + CSR build ----
    ktconv_k<<<9, blk, 0, stream>>>(rel_k, self_k, Kth, Ktl);
    hipMemsetAsync(cnt, 0, (size_t)NSEG * sizeof(unsigned), stream);
    count_k<<<NETOT / 256, blk, 0, stream>>>(edge_src, cnt);
    scan1_k<<<NB1, blk, 0, stream>>>(cnt, offs, bsum);
    scan2_k<<<1, blk, 0, stream>>>(bsum, NB1);
    scan3_k<<<NB1, blk, 0, stream>>>(offs, bsum);
    hipMemsetAsync(cnt, 0, (size_t)NSEG * sizeof(unsigned), stream);
    fill_k<<<NETOT / 256, blk, 0, stream>>>(edge_src, edge_dst, edge_val,
                                            offs, cnt, recs);

    // ---- aggregate-first: B_r = segsum_r(emb); A (+)= B @ vstack(K_r) ----
    const int gy = (N_ENT + 127) / 128;     // 782
    int first = 1;
    for (int g0 = 0; g0 < RR; ) {
        int nr = (RR - g0 < RPG) ? RR - g0 : RPG;
        launch_segsum(nr, offs + (size_t)g0 * N_ENT, recs, emb, Bbuf, stream);
        if (first)
            gemm_mfma_k<false, false><<<gy, blk, 0, stream>>>(
                Bbuf, nr * 128,
                Kth + (size_t)g0 * 16384, Ktl + (size_t)g0 * 16384, nr,
                nullptr, nullptr, A, N_ENT);
        else
            gemm_mfma_k<false, true><<<gy, blk, 0, stream>>>(
                Bbuf, nr * 128,
                Kth + (size_t)g0 * 16384, Ktl + (size_t)g0 * 16384, nr,
                nullptr, nullptr, A, N_ENT);
        first = 0;
        g0 += nr;
    }

    // ---- final: out = sigmoid(X @ S + A[idx]) ----
    const int gb = (NB + 127) / 128;        // 391
    gemm_mfma_k<true, false><<<gb, blk, 0, stream>>>(
        head_e, 128, Kth + (size_t)8 * 16384, Ktl + (size_t)8 * 16384, 1,
        A, head_idx, out, NB);
    gemm_mfma_k<true, false><<<gb, blk, 0, stream>>>(
        tail_e, 128, Kth + (size_t)8 * 16384, Ktl + (size_t)8 * 16384, 1,
        A, tail_idx, out + (size_t)NB * 128, NB);
}

// Round 3
// 676.534 us; speedup vs baseline: 1.0594x; 1.0182x over previous
//
#include <hip/hip_runtime.h>
#include <hip/hip_bf16.h>
#include <math.h>

#define N_ENT 100000
#define NB    50000
#define NE    200000
#define RR    8
#define NETOT (RR * NE)          // 1,600,000
#define NSEG  (RR * N_ENT)       // 800,000

typedef float f32x4  __attribute__((ext_vector_type(4)));
typedef short s16x8  __attribute__((ext_vector_type(8)));

__device__ __forceinline__ void split2(float x, short& h, short& l)
{
    unsigned uh = __float_as_uint(x) & 0xffff0000u;
    h = (short)(uh >> 16);
    float r = x - __uint_as_float(uh);
    l = (short)(__float_as_uint(r) >> 16);
}

// ---------------- K pre-transform: Kt[r][o][d] = K[r][d][o], split hi/lo bf16 ---
__global__ __launch_bounds__(256)
void ktconv_k(const float* __restrict__ rel_k, const float* __restrict__ self_k,
              short* __restrict__ Kth, short* __restrict__ Ktl)
{
    const int r = blockIdx.x;              // 0..8, 8 == self
    const float* src = (r < 8) ? rel_k + (size_t)r * 16384 : self_k;
    short* oh = Kth + (size_t)r * 16384;
    short* ol = Ktl + (size_t)r * 16384;
    for (int i = 0; i < 64; ++i) {
        int ix = i * 256 + threadIdx.x;    // 0..16383
        int d = ix >> 7, o = ix & 127;
        short h, l;
        split2(src[ix], h, l);
        oh[o * 128 + d] = h;
        ol[o * 128 + d] = l;
    }
}

// ---------------- MFMA GEMM: out[rows x 128] = X @ Kstack (+ optional epilogues)
// block: 256 thr / 4 waves, 128 rows per block.
// X row stride = xstride floats; K = nkc chunks of 128 (each chunk = one 128x128
// transposed hi/lo Kt staged into LDS).
// FINAL: out = sigmoid(acc + Abuf[idx[row]])   ACCUM: out += acc   else: out = acc
template<bool FINAL, bool ACCUM>
__global__ __launch_bounds__(256)
void gemm_mfma_k(const float* __restrict__ X, int xstride,
                 const short* __restrict__ Kth, const short* __restrict__ Ktl,
                 int nkc,
                 const float* __restrict__ Abuf, const int* __restrict__ idx,
                 float* __restrict__ out, int nrows)
{
    __shared__ short Bh[128][136];   // padded: 272B row stride -> conflict-free-ish
    __shared__ short Bl[128][136];

    const int t     = threadIdx.x;
    const int wv    = t >> 6;
    const int lane  = t & 63;
    const int col16 = lane & 15;
    const int g     = lane >> 4;          // k-group 0..3
    const int rowbase = blockIdx.x * 128 + wv * 32;

    f32x4 acc[2][8];
#pragma unroll
    for (int m = 0; m < 2; ++m)
#pragma unroll
        for (int c = 0; c < 8; ++c) acc[m][c] = (f32x4){0.f, 0.f, 0.f, 0.f};

    for (int kc = 0; kc < nkc; ++kc) {
        __syncthreads();                  // protect LDS from previous chunk's reads
        {
            const s16x8* gh = (const s16x8*)(Kth + (size_t)kc * 16384);
            const s16x8* gl = (const s16x8*)(Ktl + (size_t)kc * 16384);
#pragma unroll
            for (int i = 0; i < 8; ++i) {
                int f = t + i * 256;          // 0..2047
                int o = f >> 4, c = f & 15;
                *(s16x8*)&Bh[o][c * 8] = gh[f];
                *(s16x8*)&Bl[o][c * 8] = gl[f];
            }
        }
        __syncthreads();

#pragma unroll
        for (int s = 0; s < 4; ++s) {
            s16x8 ah[2], al[2];
#pragma unroll
            for (int m = 0; m < 2; ++m) {
                int r = rowbase + m * 16 + col16;
                if (r > nrows - 1) r = nrows - 1;
                const float* xp = X + (size_t)r * xstride + kc * 128 + s * 32 + g * 8;
                float4 u0 = *(const float4*)xp;
                float4 u1 = *(const float4*)(xp + 4);
                float u[8] = {u0.x, u0.y, u0.z, u0.w, u1.x, u1.y, u1.z, u1.w};
#pragma unroll
                for (int j = 0; j < 8; ++j) {
                    short h, l; split2(u[j], h, l);
                    ah[m][j] = h; al[m][j] = l;
                }
            }
#pragma unroll
            for (int c = 0; c < 8; ++c) {
                s16x8 bh = *(const s16x8*)&Bh[c * 16 + col16][s * 32 + g * 8];
                s16x8 bl = *(const s16x8*)&Bl[c * 16 + col16][s * 32 + g * 8];
#pragma unroll
                for (int m = 0; m < 2; ++m) {
                    acc[m][c] = __builtin_amdgcn_mfma_f32_16x16x32_bf16(ah[m], bh, acc[m][c], 0, 0, 0);
                    acc[m][c] = __builtin_amdgcn_mfma_f32_16x16x32_bf16(ah[m], bl, acc[m][c], 0, 0, 0);
                    acc[m][c] = __builtin_amdgcn_mfma_f32_16x16x32_bf16(al[m], bh, acc[m][c], 0, 0, 0);
                }
            }
        }
    }

    // epilogue: C layout col=lane&15, row=g*4+reg
#pragma unroll
    for (int m = 0; m < 2; ++m) {
#pragma unroll
        for (int j = 0; j < 4; ++j) {
            int row = rowbase + m * 16 + g * 4 + j;
            if (row >= nrows) continue;
            float* op = out + (size_t)row * 128;
            if (FINAL) {
                int gi = idx[row];
                const float* Ar = Abuf + (size_t)gi * 128;
#pragma unroll
                for (int c = 0; c < 8; ++c) {
                    int col = c * 16 + col16;
                    float x = acc[m][c][j] + Ar[col];
                    op[col] = 1.f / (1.f + __expf(-x));
                }
            } else if (ACCUM) {
#pragma unroll
                for (int c = 0; c < 8; ++c) {
                    int col = c * 16 + col16;
                    op[col] += acc[m][c][j];
                }
            } else {
#pragma unroll
                for (int c = 0; c < 8; ++c)
                    op[c * 16 + col16] = acc[m][c][j];
            }
        }
    }
}

// ---------------- CSR build (4 edges/thread for MLP) ----------------
__global__ __launch_bounds__(256)
void count_k(const int* __restrict__ edge_src, unsigned* __restrict__ cnt)
{
    int base = (blockIdx.x * 256 + threadIdx.x) * 4;
    if (base >= NETOT) return;
    int r = base / NE;                     // NE % 4 == 0 -> pack never crosses r
    int4 s4 = *(const int4*)(edge_src + base);
    atomicAdd(&cnt[r * N_ENT + s4.x], 1u);
    atomicAdd(&cnt[r * N_ENT + s4.y], 1u);
    atomicAdd(&cnt[r * N_ENT + s4.z], 1u);
    atomicAdd(&cnt[r * N_ENT + s4.w], 1u);
}

__global__ __launch_bounds__(256)
void scan1_k(const unsigned* __restrict__ cnt, unsigned* __restrict__ offs,
             unsigned* __restrict__ bsum)
{
    __shared__ unsigned s[256];
    const int t = threadIdx.x;
    const int base = blockIdx.x * 1024;
    unsigned v[4], sum = 0;
#pragma unroll
    for (int i = 0; i < 4; ++i) {
        int ix = base + t * 4 + i;
        v[i] = (ix < NSEG) ? cnt[ix] : 0u;
        sum += v[i];
    }
    s[t] = sum; __syncthreads();
    for (int off = 1; off < 256; off <<= 1) {
        unsigned x = (t >= off) ? s[t - off] : 0u;
        __syncthreads();
        s[t] += x;
        __syncthreads();
    }
    unsigned run = s[t] - sum;
#pragma unroll
    for (int i = 0; i < 4; ++i) {
        int ix = base + t * 4 + i;
        if (ix < NSEG) offs[ix] = run;
        run += v[i];
    }
    if (t == 255) bsum[blockIdx.x] = s[255];
}

__global__ __launch_bounds__(256)
void scan2_k(unsigned* __restrict__ bsum, int nb)
{
    __shared__ unsigned s[256];
    __shared__ unsigned carry;
    const int t = threadIdx.x;
    if (t == 0) carry = 0;
    __syncthreads();
    for (int base = 0; base < nb; base += 256) {
        unsigned v = (base + t < nb) ? bsum[base + t] : 0u;
        s[t] = v; __syncthreads();
        for (int off = 1; off < 256; off <<= 1) {
            unsigned x = (t >= off) ? s[t - off] : 0u;
            __syncthreads();
            s[t] += x;
            __syncthreads();
        }
        unsigned tot = s[255];
        unsigned excl = s[t] - v + carry;
        if (base + t < nb) bsum[base + t] = excl;
        __syncthreads();
        if (t == 0) carry += tot;
        __syncthreads();
    }
}

__global__ __launch_bounds__(256)
void scan3_k(unsigned* __restrict__ offs, const unsigned* __restrict__ bsum)
{
    const int base = blockIdx.x * 1024;
    unsigned add = bsum[blockIdx.x];
#pragma unroll
    for (int i = 0; i < 4; ++i) {
        int ix = base + threadIdx.x * 4 + i;
        if (ix < NSEG) offs[ix] += add;
    }
    if (blockIdx.x == 0 && threadIdx.x == 0) offs[NSEG] = NETOT;
}

__global__ __launch_bounds__(256)
void fill_k(const int* __restrict__ edge_src, const int* __restrict__ edge_dst,
            const float* __restrict__ edge_val,
            const unsigned* __restrict__ offs, unsigned* __restrict__ cursor,
            int2* __restrict__ recs)
{
    int base = (blockIdx.x * 256 + threadIdx.x) * 4;
    if (base >= NETOT) return;
    int r = base / NE;                     // pack never crosses relation boundary
    int4   src4 = *(const int4*)(edge_src + base);
    int4   dst4 = *(const int4*)(edge_dst + base);
    float4 val4 = *(const float4*)(edge_val + base);
    int sg[4] = { r * N_ENT + src4.x, r * N_ENT + src4.y,
                  r * N_ENT + src4.z, r * N_ENT + src4.w };
    unsigned off[4];
#pragma unroll
    for (int i = 0; i < 4; ++i) off[i] = offs[sg[i]];       // independent loads
    unsigned pos[4];
#pragma unroll
    for (int i = 0; i < 4; ++i) pos[i] = atomicAdd(&cursor[sg[i]], 1u);  // independent atomics
    int d[4] = { dst4.x, dst4.y, dst4.z, dst4.w };
    float v[4] = { val4.x, val4.y, val4.z, val4.w };
#pragma unroll
    for (int i = 0; i < 4; ++i) {
        int2 rec; rec.x = d[i]; rec.y = __float_as_int(v[i]);
        recs[off[i] + pos[i]] = rec;
    }
}

// ---------------- fused aggregate-first segment-sum ----------------
// one wave per segment s, covering all NR relations of the group.
// ALL loads are unconditional (index-clamped) so rec loads and emb gathers
// stay batched in flight; pad slots duplicate the last real record's address
// (L1 hit) and contribute 0 via val=0 (exact no-op, FMA order preserved).
template<int NR>
__global__ __launch_bounds__(256)
void segsum_k(const unsigned* __restrict__ offs_r, const int2* __restrict__ recs,
              const float* __restrict__ emb, float* __restrict__ B)
{
    constexpr int T = 4;
    const int s    = (blockIdx.x * 256 + threadIdx.x) >> 6;   // segment id
    const int lane = threadIdx.x & 63;
    if (s >= N_ENT) return;

    unsigned a[NR], b[NR];
#pragma unroll
    for (int j = 0; j < NR; ++j) {
        a[j] = offs_r[(size_t)j * N_ENT + s];
        b[j] = offs_r[(size_t)j * N_ENT + s + 1];
    }
    int n[NR];
#pragma unroll
    for (int j = 0; j < NR; ++j) n[j] = (int)(b[j] - a[j]);

    // phase 1: unconditional clamped record loads (NR*T independent)
    int2 rec[NR][T];
#pragma unroll
    for (int j = 0; j < NR; ++j) {
#pragma unroll
        for (int i = 0; i < T; ++i) {
            int ii = (i < n[j]) ? i : (n[j] - 1);
            if (ii < 0) ii = 0;
            unsigned pos = a[j] + (unsigned)ii;
            if (pos > (unsigned)(NETOT - 1)) pos = NETOT - 1;
            rec[j][i] = recs[pos];
        }
    }

    // phase 2: unconditional emb gathers (NR*T independent 512B row reads)
    float2 y[NR][T];
#pragma unroll
    for (int j = 0; j < NR; ++j)
#pragma unroll
        for (int i = 0; i < T; ++i)
            y[j][i] = *(const float2*)(emb + (size_t)rec[j][i].x * 128 + lane * 2);

    // phase 3: accumulate; pads contribute exactly 0
    float2 acc[NR];
#pragma unroll
    for (int j = 0; j < NR; ++j) acc[j] = (float2){0.f, 0.f};
#pragma unroll
    for (int j = 0; j < NR; ++j)
#pragma unroll
        for (int i = 0; i < T; ++i) {
            float v = (i < n[j]) ? __int_as_float(rec[j][i].y) : 0.f;
            acc[j].x = fmaf(v, y[j][i].x, acc[j].x);
            acc[j].y = fmaf(v, y[j][i].y, acc[j].y);
        }

    // tail: segments with > T edges (rare, wave-uniform)
#pragma unroll
    for (int j = 0; j < NR; ++j) {
        for (int i = T; i < n[j]; ++i) {
            int2 rc = recs[a[j] + i];
            float v = __int_as_float(rc.y);
            float2 yy = *(const float2*)(emb + (size_t)rc.x * 128 + lane * 2);
            acc[j].x = fmaf(v, yy.x, acc[j].x);
            acc[j].y = fmaf(v, yy.y, acc[j].y);
        }
    }

#pragma unroll
    for (int j = 0; j < NR; ++j)
        *(float2*)(B + ((size_t)s * NR + j) * 128 + lane * 2) = acc[j];
}

static void launch_segsum(int nr, const unsigned* offs_r, const int2* recs,
                          const float* emb, float* B, hipStream_t stream)
{
    dim3 blk(256);
    const int blocks = (N_ENT * 64) / 256;   // 25000, exact
    switch (nr) {
    case 1: segsum_k<1><<<blocks, blk, 0, stream>>>(offs_r, recs, emb, B); break;
    case 2: segsum_k<2><<<blocks, blk, 0, stream>>>(offs_r, recs, emb, B); break;
    case 3: segsum_k<3><<<blocks, blk, 0, stream>>>(offs_r, recs, emb, B); break;
    default: segsum_k<4><<<blocks, blk, 0, stream>>>(offs_r, recs, emb, B); break;
    }
}

extern "C" void kernel_launch(void* const* d_in, const int* in_sizes, int n_in,
                              void* d_out, int out_size, void* d_ws, size_t ws_size,
                              hipStream_t stream)
{
    const float* emb      = (const float*)d_in[0];
    const float* head_e   = (const float*)d_in[1];
    const float* tail_e   = (const float*)d_in[2];
    const float* rel_k    = (const float*)d_in[3];
    const float* self_k   = (const float*)d_in[4];
    const float* edge_val = (const float*)d_in[5];
    const int*   head_idx = (const int*)d_in[6];
    const int*   tail_idx = (const int*)d_in[7];
    const int*   edge_src = (const int*)d_in[8];
    const int*   edge_dst = (const int*)d_in[9];
    float* out = (float*)d_out;

    // workspace layout (each region 256B-aligned)
    char* p = (char*)d_ws;
    auto take = [&](size_t bytes) -> char* {
        char* q = p; p += (bytes + 255) & ~(size_t)255; return q;
    };
    float*    A    = (float*)take((size_t)N_ENT * 128 * sizeof(float));     // 51.2 MB
    int2*     recs = (int2*)take((size_t)NETOT * sizeof(int2));             // 12.8 MB
    unsigned* cnt  = (unsigned*)take((size_t)NSEG * sizeof(unsigned));      //  3.2 MB
    unsigned* offs = (unsigned*)take(((size_t)NSEG + 1) * sizeof(unsigned));//  3.2 MB
    unsigned* bsum = (unsigned*)take(1024 * sizeof(unsigned));
    short*    Kth  = (short*)take((size_t)9 * 16384 * sizeof(short));       //  0.3 MB
    short*    Ktl  = (short*)take((size_t)9 * 16384 * sizeof(short));       //  0.3 MB
    float*    Bbuf = (float*)p;                                             // rest

    // adaptive relation-group size: how many 51.2 MB B_r slices fit?
    size_t used    = (size_t)(p - (char*)d_ws);
    size_t avail   = (ws_size > used) ? ws_size - used : 0;
    size_t per_rel = (size_t)N_ENT * 128 * sizeof(float);
    int RPG = (int)(avail / per_rel);
    if (RPG > 4) RPG = 4;    // template max; ILP gain saturates here
    if (RPG < 1) RPG = 1;

    const int NB1 = (NSEG + 1023) / 1024;     // 782
    const int EB  = (NETOT + 1023) / 1024;    // 1563 (4 edges/thread)
    dim3 blk(256);

    // ---- K transform + CSR build ----
    ktconv_k<<<9, blk, 0, stream>>>(rel_k, self_k, Kth, Ktl);
    hipMemsetAsync(cnt, 0, (size_t)NSEG * sizeof(unsigned), stream);
    count_k<<<EB, blk, 0, stream>>>(edge_src, cnt);
    scan1_k<<<NB1, blk, 0, stream>>>(cnt, offs, bsum);
    scan2_k<<<1, blk, 0, stream>>>(bsum, NB1);
    scan3_k<<<NB1, blk, 0, stream>>>(offs, bsum);
    hipMemsetAsync(cnt, 0, (size_t)NSEG * sizeof(unsigned), stream);
    fill_k<<<EB, blk, 0, stream>>>(edge_src, edge_dst, edge_val,
                                   offs, cnt, recs);

    // ---- aggregate-first: B_r = segsum_r(emb); A (+)= B @ vstack(K_r) ----
    const int gy = (N_ENT + 127) / 128;     // 782
    int first = 1;
    for (int g0 = 0; g0 < RR; ) {
        int nr = (RR - g0 < RPG) ? RR - g0 : RPG;
        launch_segsum(nr, offs + (size_t)g0 * N_ENT, recs, emb, Bbuf, stream);
        if (first)
            gemm_mfma_k<false, false><<<gy, blk, 0, stream>>>(
                Bbuf, nr * 128,
                Kth + (size_t)g0 * 16384, Ktl + (size_t)g0 * 16384, nr,
                nullptr, nullptr, A, N_ENT);
        else
            gemm_mfma_k<false, true><<<gy, blk, 0, stream>>>(
                Bbuf, nr * 128,
                Kth + (size_t)g0 * 16384, Ktl + (size_t)g0 * 16384, nr,
                nullptr, nullptr, A, N_ENT);
        first = 0;
        g0 += nr;
    }

    // ---- final: out = sigmoid(X @ S + A[idx]) ----
    const int gb = (NB + 127) / 128;        // 391
    gemm_mfma_k<true, false><<<gb, blk, 0, stream>>>(
        head_e, 128, Kth + (size_t)8 * 16384, Ktl + (size_t)8 * 16384, 1,
        A, head_idx, out, NB);
    gemm_mfma_k<true, false><<<gb, blk, 0, stream>>>(
        tail_e, 128, Kth + (size_t)8 * 16384, Ktl + (size_t)8 * 16384, 1,
        A, tail_idx, out + (size_t)NB * 128, NB);
}

// Round 4
// 616.317 us; speedup vs baseline: 1.1629x; 1.0977x over previous
//
#include <hip/hip_runtime.h>
#include <hip/hip_bf16.h>
#include <math.h>

#define N_ENT 100000
#define NB    50000
#define NE    200000
#define RR    8
#define NETOT (RR * NE)          // 1,600,000
#define NSEG  (RR * N_ENT)       // 800,000

typedef float f32x4  __attribute__((ext_vector_type(4)));
typedef short s16x8  __attribute__((ext_vector_type(8)));

__device__ __forceinline__ void split2(float x, short& h, short& l)
{
    unsigned uh = __float_as_uint(x) & 0xffff0000u;
    h = (short)(uh >> 16);
    float r = x - __uint_as_float(uh);
    l = (short)(__float_as_uint(r) >> 16);
}

// async global->LDS: each lane copies 16B from its own global addr; LDS dest is
// wave-uniform base + lane*16. No VGPR destination -> loads can't be serialized
// by the register allocator; tracked by vmcnt only.
__device__ __forceinline__ void glds16(const float* g, float* l)
{
    __builtin_amdgcn_global_load_lds(
        (const __attribute__((address_space(1))) void*)g,
        (__attribute__((address_space(3))) void*)l, 16, 0, 0);
}

// ---------------- K pre-transform: Kt[r][o][d] = K[r][d][o], split hi/lo bf16 ---
__global__ __launch_bounds__(256)
void ktconv_k(const float* __restrict__ rel_k, const float* __restrict__ self_k,
              short* __restrict__ Kth, short* __restrict__ Ktl)
{
    const int r = blockIdx.x;              // 0..8, 8 == self
    const float* src = (r < 8) ? rel_k + (size_t)r * 16384 : self_k;
    short* oh = Kth + (size_t)r * 16384;
    short* ol = Ktl + (size_t)r * 16384;
    for (int i = 0; i < 64; ++i) {
        int ix = i * 256 + threadIdx.x;    // 0..16383
        int d = ix >> 7, o = ix & 127;
        short h, l;
        split2(src[ix], h, l);
        oh[o * 128 + d] = h;
        ol[o * 128 + d] = l;
    }
}

// ---------------- MFMA GEMM: out[rows x 128] = X @ Kstack (+ optional epilogues)
template<bool FINAL, bool ACCUM>
__global__ __launch_bounds__(256)
void gemm_mfma_k(const float* __restrict__ X, int xstride,
                 const short* __restrict__ Kth, const short* __restrict__ Ktl,
                 int nkc,
                 const float* __restrict__ Abuf, const int* __restrict__ idx,
                 float* __restrict__ out, int nrows)
{
    __shared__ short Bh[128][136];   // padded: 272B row stride -> conflict-free-ish
    __shared__ short Bl[128][136];

    const int t     = threadIdx.x;
    const int wv    = t >> 6;
    const int lane  = t & 63;
    const int col16 = lane & 15;
    const int g     = lane >> 4;          // k-group 0..3
    const int rowbase = blockIdx.x * 128 + wv * 32;

    f32x4 acc[2][8];
#pragma unroll
    for (int m = 0; m < 2; ++m)
#pragma unroll
        for (int c = 0; c < 8; ++c) acc[m][c] = (f32x4){0.f, 0.f, 0.f, 0.f};

    for (int kc = 0; kc < nkc; ++kc) {
        __syncthreads();                  // protect LDS from previous chunk's reads
        {
            const s16x8* gh = (const s16x8*)(Kth + (size_t)kc * 16384);
            const s16x8* gl = (const s16x8*)(Ktl + (size_t)kc * 16384);
#pragma unroll
            for (int i = 0; i < 8; ++i) {
                int f = t + i * 256;          // 0..2047
                int o = f >> 4, c = f & 15;
                *(s16x8*)&Bh[o][c * 8] = gh[f];
                *(s16x8*)&Bl[o][c * 8] = gl[f];
            }
        }
        __syncthreads();

#pragma unroll
        for (int s = 0; s < 4; ++s) {
            s16x8 ah[2], al[2];
#pragma unroll
            for (int m = 0; m < 2; ++m) {
                int r = rowbase + m * 16 + col16;
                if (r > nrows - 1) r = nrows - 1;
                const float* xp = X + (size_t)r * xstride + kc * 128 + s * 32 + g * 8;
                float4 u0 = *(const float4*)xp;
                float4 u1 = *(const float4*)(xp + 4);
                float u[8] = {u0.x, u0.y, u0.z, u0.w, u1.x, u1.y, u1.z, u1.w};
#pragma unroll
                for (int j = 0; j < 8; ++j) {
                    short h, l; split2(u[j], h, l);
                    ah[m][j] = h; al[m][j] = l;
                }
            }
#pragma unroll
            for (int c = 0; c < 8; ++c) {
                s16x8 bh = *(const s16x8*)&Bh[c * 16 + col16][s * 32 + g * 8];
                s16x8 bl = *(const s16x8*)&Bl[c * 16 + col16][s * 32 + g * 8];
#pragma unroll
                for (int m = 0; m < 2; ++m) {
                    acc[m][c] = __builtin_amdgcn_mfma_f32_16x16x32_bf16(ah[m], bh, acc[m][c], 0, 0, 0);
                    acc[m][c] = __builtin_amdgcn_mfma_f32_16x16x32_bf16(ah[m], bl, acc[m][c], 0, 0, 0);
                    acc[m][c] = __builtin_amdgcn_mfma_f32_16x16x32_bf16(al[m], bh, acc[m][c], 0, 0, 0);
                }
            }
        }
    }

    // epilogue: C layout col=lane&15, row=g*4+reg
#pragma unroll
    for (int m = 0; m < 2; ++m) {
#pragma unroll
        for (int j = 0; j < 4; ++j) {
            int row = rowbase + m * 16 + g * 4 + j;
            if (row >= nrows) continue;
            float* op = out + (size_t)row * 128;
            if (FINAL) {
                int gi = idx[row];
                const float* Ar = Abuf + (size_t)gi * 128;
#pragma unroll
                for (int c = 0; c < 8; ++c) {
                    int col = c * 16 + col16;
                    float x = acc[m][c][j] + Ar[col];
                    op[col] = 1.f / (1.f + __expf(-x));
                }
            } else if (ACCUM) {
#pragma unroll
                for (int c = 0; c < 8; ++c) {
                    int col = c * 16 + col16;
                    op[col] += acc[m][c][j];
                }
            } else {
#pragma unroll
                for (int c = 0; c < 8; ++c)
                    op[c * 16 + col16] = acc[m][c][j];
            }
        }
    }
}

// ---------------- CSR build (1 edge/thread; count emits per-edge rank) --------
__global__ __launch_bounds__(256)
void count_k(const int* __restrict__ edge_src, unsigned* __restrict__ cnt,
             unsigned char* __restrict__ rank)
{
    int g = blockIdx.x * 256 + threadIdx.x;
    int r = g / NE;
    int src = edge_src[g];
    unsigned old = atomicAdd(&cnt[r * N_ENT + src], 1u);
    rank[g] = (unsigned char)old;          // segment sizes << 256 (Poisson(2))
}

__global__ __launch_bounds__(256)
void scan1_k(const unsigned* __restrict__ cnt, unsigned* __restrict__ offs,
             unsigned* __restrict__ bsum)
{
    __shared__ unsigned s[256];
    const int t = threadIdx.x;
    const int base = blockIdx.x * 1024;
    unsigned v[4], sum = 0;
#pragma unroll
    for (int i = 0; i < 4; ++i) {
        int ix = base + t * 4 + i;
        v[i] = (ix < NSEG) ? cnt[ix] : 0u;
        sum += v[i];
    }
    s[t] = sum; __syncthreads();
    for (int off = 1; off < 256; off <<= 1) {
        unsigned x = (t >= off) ? s[t - off] : 0u;
        __syncthreads();
        s[t] += x;
        __syncthreads();
    }
    unsigned run = s[t] - sum;
#pragma unroll
    for (int i = 0; i < 4; ++i) {
        int ix = base + t * 4 + i;
        if (ix < NSEG) offs[ix] = run;
        run += v[i];
    }
    if (t == 255) bsum[blockIdx.x] = s[255];
}

__global__ __launch_bounds__(256)
void scan2_k(unsigned* __restrict__ bsum, int nb)
{
    __shared__ unsigned s[256];
    __shared__ unsigned carry;
    const int t = threadIdx.x;
    if (t == 0) carry = 0;
    __syncthreads();
    for (int base = 0; base < nb; base += 256) {
        unsigned v = (base + t < nb) ? bsum[base + t] : 0u;
        s[t] = v; __syncthreads();
        for (int off = 1; off < 256; off <<= 1) {
            unsigned x = (t >= off) ? s[t - off] : 0u;
            __syncthreads();
            s[t] += x;
            __syncthreads();
        }
        unsigned tot = s[255];
        unsigned excl = s[t] - v + carry;
        if (base + t < nb) bsum[base + t] = excl;
        __syncthreads();
        if (t == 0) carry += tot;
        __syncthreads();
    }
}

__global__ __launch_bounds__(256)
void scan3_k(unsigned* __restrict__ offs, const unsigned* __restrict__ bsum)
{
    const int base = blockIdx.x * 1024;
    unsigned add = bsum[blockIdx.x];
#pragma unroll
    for (int i = 0; i < 4; ++i) {
        int ix = base + threadIdx.x * 4 + i;
        if (ix < NSEG) offs[ix] += add;
    }
    if (blockIdx.x == 0 && threadIdx.x == 0) offs[NSEG] = NETOT;
}

// fill with precomputed rank: no atomic, no cursor pass
__global__ __launch_bounds__(256)
void fill_k(const int* __restrict__ edge_src, const int* __restrict__ edge_dst,
            const float* __restrict__ edge_val,
            const unsigned* __restrict__ offs,
            const unsigned char* __restrict__ rank,
            int2* __restrict__ recs)
{
    int g = blockIdx.x * 256 + threadIdx.x;
    int r = g / NE;
    int src = edge_src[g];
    int seg = r * N_ENT + src;
    unsigned pos = offs[seg] + rank[g];
    int2 rec;
    rec.x = edge_dst[g];
    rec.y = __float_as_int(edge_val[g]);
    recs[pos] = rec;
}

// ---------------- fused aggregate-first segment-sum ----------------
// One wave per segment s, covering NR relations. Row gathers are issued as
// async global_load_lds (2 rows per dwordx4 instruction, no VGPR dest), so all
// NR*T gathers are in flight simultaneously regardless of regalloc decisions.
// Pads duplicate a real record's address and contribute 0 via v=0 (exact).
template<int NR>
__global__ __launch_bounds__(256)
void segsum_k(const unsigned* __restrict__ offs_r, const int2* __restrict__ recs,
              const float* __restrict__ emb, float* __restrict__ B)
{
    constexpr int T = 4;                       // slots per relation (even)
    constexpr int SLOTS = NR * T;
    __shared__ float stage[4][SLOTS * 128];    // per-wave staging, 512B per slot

    const int s    = (blockIdx.x * 256 + threadIdx.x) >> 6;   // segment id
    const int wv   = threadIdx.x >> 6;
    const int lane = threadIdx.x & 63;
    if (s >= N_ENT) return;                    // grid is exact; safety only

    unsigned a[NR]; int n[NR];
#pragma unroll
    for (int j = 0; j < NR; ++j) {
        unsigned lo = offs_r[(size_t)j * N_ENT + s];
        unsigned hi = offs_r[(size_t)j * N_ENT + s + 1];
        a[j] = lo; n[j] = (int)(hi - lo);
    }

    // phase 1: clamped, unconditional record loads (NR*T independent 8B)
    int2 rec[NR][T];
#pragma unroll
    for (int j = 0; j < NR; ++j) {
#pragma unroll
        for (int i = 0; i < T; ++i) {
            int ii = (i < n[j]) ? i : (n[j] - 1);
            if (ii < 0) ii = 0;
            unsigned pos = a[j] + (unsigned)ii;
            if (pos > (unsigned)(NETOT - 1)) pos = NETOT - 1;
            rec[j][i] = recs[pos];
        }
    }

    // phase 2: async gather all rows into LDS. One dwordx4 covers 2 rows:
    // lanes 0-31 stream row(2*ip), lanes 32-63 stream row(2*ip+1).
    float* myst = &stage[wv][0];
#pragma unroll
    for (int j = 0; j < NR; ++j) {
#pragma unroll
        for (int ip = 0; ip < T / 2; ++ip) {
            int r0 = rec[j][2 * ip].x;
            int r1 = rec[j][2 * ip + 1].x;
            int row = (lane < 32) ? r0 : r1;
            const float* g = emb + (size_t)row * 128 + (lane & 31) * 4;
            glds16(g, myst + (j * T + 2 * ip) * 128);
        }
    }
    asm volatile("s_waitcnt vmcnt(0)" ::: "memory");
    __builtin_amdgcn_sched_barrier(0);

    // phase 3: read back + accumulate (same per-segment FMA order as serial)
    float2 acc[NR];
#pragma unroll
    for (int j = 0; j < NR; ++j) acc[j] = (float2){0.f, 0.f};
#pragma unroll
    for (int j = 0; j < NR; ++j)
#pragma unroll
        for (int i = 0; i < T; ++i) {
            float2 y = *(const float2*)&myst[(j * T + i) * 128 + lane * 2];
            float v = (i < n[j]) ? __int_as_float(rec[j][i].y) : 0.f;
            acc[j].x = fmaf(v, y.x, acc[j].x);
            acc[j].y = fmaf(v, y.y, acc[j].y);
        }

    // tail: segments with > T edges (rare, wave-uniform)
#pragma unroll
    for (int j = 0; j < NR; ++j) {
        for (int i = T; i < n[j]; ++i) {
            int2 rc = recs[a[j] + i];
            float v = __int_as_float(rc.y);
            float2 yy = *(const float2*)(emb + (size_t)rc.x * 128 + lane * 2);
            acc[j].x = fmaf(v, yy.x, acc[j].x);
            acc[j].y = fmaf(v, yy.y, acc[j].y);
        }
    }

#pragma unroll
    for (int j = 0; j < NR; ++j)
        *(float2*)(B + ((size_t)s * NR + j) * 128 + lane * 2) = acc[j];
}

static void launch_segsum(int nr, const unsigned* offs_r, const int2* recs,
                          const float* emb, float* B, hipStream_t stream)
{
    dim3 blk(256);
    const int blocks = (N_ENT * 64) / 256;   // 25000, exact
    switch (nr) {
    case 1: segsum_k<1><<<blocks, blk, 0, stream>>>(offs_r, recs, emb, B); break;
    case 2: segsum_k<2><<<blocks, blk, 0, stream>>>(offs_r, recs, emb, B); break;
    case 3: segsum_k<3><<<blocks, blk, 0, stream>>>(offs_r, recs, emb, B); break;
    default: segsum_k<4><<<blocks, blk, 0, stream>>>(offs_r, recs, emb, B); break;
    }
}

extern "C" void kernel_launch(void* const* d_in, const int* in_sizes, int n_in,
                              void* d_out, int out_size, void* d_ws, size_t ws_size,
                              hipStream_t stream)
{
    const float* emb      = (const float*)d_in[0];
    const float* head_e   = (const float*)d_in[1];
    const float* tail_e   = (const float*)d_in[2];
    const float* rel_k    = (const float*)d_in[3];
    const float* self_k   = (const float*)d_in[4];
    const float* edge_val = (const float*)d_in[5];
    const int*   head_idx = (const int*)d_in[6];
    const int*   tail_idx = (const int*)d_in[7];
    const int*   edge_src = (const int*)d_in[8];
    const int*   edge_dst = (const int*)d_in[9];
    float* out = (float*)d_out;

    // workspace layout (each region 256B-aligned)
    char* p = (char*)d_ws;
    auto take = [&](size_t bytes) -> char* {
        char* q = p; p += (bytes + 255) & ~(size_t)255; return q;
    };
    float*         A    = (float*)take((size_t)N_ENT * 128 * sizeof(float));     // 51.2 MB
    int2*          recs = (int2*)take((size_t)NETOT * sizeof(int2));             // 12.8 MB
    unsigned*      cnt  = (unsigned*)take((size_t)NSEG * sizeof(unsigned));      //  3.2 MB
    unsigned*      offs = (unsigned*)take(((size_t)NSEG + 1) * sizeof(unsigned));//  3.2 MB
    unsigned*      bsum = (unsigned*)take(1024 * sizeof(unsigned));
    unsigned char* rank = (unsigned char*)take((size_t)NETOT);                   //  1.6 MB
    short*         Kth  = (short*)take((size_t)9 * 16384 * sizeof(short));       //  0.3 MB
    short*         Ktl  = (short*)take((size_t)9 * 16384 * sizeof(short));       //  0.3 MB
    float*         Bbuf = (float*)p;                                             // rest

    // adaptive relation-group size: how many 51.2 MB B_r slices fit?
    size_t used    = (size_t)(p - (char*)d_ws);
    size_t avail   = (ws_size > used) ? ws_size - used : 0;
    size_t per_rel = (size_t)N_ENT * 128 * sizeof(float);
    int RPG = (int)(avail / per_rel);
    if (RPG > 4) RPG = 4;    // template max
    if (RPG < 1) RPG = 1;

    const int NB1 = (NSEG + 1023) / 1024;     // 782
    dim3 blk(256);

    // ---- K transform + CSR build ----
    ktconv_k<<<9, blk, 0, stream>>>(rel_k, self_k, Kth, Ktl);
    hipMemsetAsync(cnt, 0, (size_t)NSEG * sizeof(unsigned), stream);
    count_k<<<NETOT / 256, blk, 0, stream>>>(edge_src, cnt, rank);
    scan1_k<<<NB1, blk, 0, stream>>>(cnt, offs, bsum);
    scan2_k<<<1, blk, 0, stream>>>(bsum, NB1);
    scan3_k<<<NB1, blk, 0, stream>>>(offs, bsum);
    fill_k<<<NETOT / 256, blk, 0, stream>>>(edge_src, edge_dst, edge_val,
                                            offs, rank, recs);

    // ---- aggregate-first: B_r = segsum_r(emb); A (+)= B @ vstack(K_r) ----
    const int gy = (N_ENT + 127) / 128;     // 782
    int first = 1;
    for (int g0 = 0; g0 < RR; ) {
        int nr = (RR - g0 < RPG) ? RR - g0 : RPG;
        launch_segsum(nr, offs + (size_t)g0 * N_ENT, recs, emb, Bbuf, stream);
        if (first)
            gemm_mfma_k<false, false><<<gy, blk, 0, stream>>>(
                Bbuf, nr * 128,
                Kth + (size_t)g0 * 16384, Ktl + (size_t)g0 * 16384, nr,
                nullptr, nullptr, A, N_ENT);
        else
            gemm_mfma_k<false, true><<<gy, blk, 0, stream>>>(
                Bbuf, nr * 128,
                Kth + (size_t)g0 * 16384, Ktl + (size_t)g0 * 16384, nr,
                nullptr, nullptr, A, N_ENT);
        first = 0;
        g0 += nr;
    }

    // ---- final: out = sigmoid(X @ S + A[idx]) ----
    const int gb = (NB + 127) / 128;        // 391
    gemm_mfma_k<true, false><<<gb, blk, 0, stream>>>(
        head_e, 128, Kth + (size_t)8 * 16384, Ktl + (size_t)8 * 16384, 1,
        A, head_idx, out, NB);
    gemm_mfma_k<true, false><<<gb, blk, 0, stream>>>(
        tail_e, 128, Kth + (size_t)8 * 16384, Ktl + (size_t)8 * 16384, 1,
        A, tail_idx, out + (size_t)NB * 128, NB);
}